// Round 5
// baseline (294.971 us; speedup 1.0000x reference)
//
#include <hip/hip_runtime.h>
#include <cstdint>
#include <cstddef>

// ---------------- problem constants ----------------
#define NMEM    128          // ensemble size W
#define WTOTAL  348194       // per-member weight row length (floats)

#define OFF_WOBS   0
#define OFF_BOBS   8192
#define OFF_WACT   8448
#define OFF_BACT   10496
#define OFF_WTGT   10752
#define OFF_BTGT   141824
#define OFF_WS0    142080
#define OFF_BS0    207616
#define OFF_WS1    207872
#define OFF_BS1    273408
#define OFF_WS2    273664
#define OFF_BS2    339200
#define OFF_WSTATE 339456
#define OFF_BSTATE 347648
#define OFF_WREW   347680
#define OFF_BREW   347936
#define OFF_WDONE  347937
#define OFF_BDONE  348193

#define OUT_REW  2097152     // 512*128*32
#define OUT_DONE 2162688     // + 512*128

#define RB 128               // rows (batch) per block -> 4 chunks/member
// pitch 264 elems = 132 dwords == 4 mod 32 -> a wave's b128 A-read spreads
// 8 lanes per 4-bank group (the even-spread minimum for 1KB/instr).
#define APITCH 264

typedef __attribute__((ext_vector_type(8))) short short8;
typedef __attribute__((ext_vector_type(4))) float f32x4;

// pack two f32 -> one dword of 2x bf16 (round-half-up): 2 adds + 1 v_perm.
__device__ __forceinline__ uint32_t pkbf2(float lo, float hi) {
  union { float f; uint32_t u; } a, b;
  a.f = lo; b.f = hi;
  return __builtin_amdgcn_perm(b.u + 0x8000u, a.u + 0x8000u, 0x07060302u);
}

__device__ __forceinline__ uint16_t f2b_fast(float f) {
  union { float f; uint32_t u; } x; x.f = f;
  return (uint16_t)((x.u + 0x8000u) >> 16);
}

__device__ __forceinline__ short8 pk8f2(const float2 f[4]) {
  union { uint32_t u[4]; short8 s; } r;
#pragma unroll
  for (int i = 0; i < 4; ++i) r.u[i] = pkbf2(f[i].x, f[i].y);
  return r.s;
}

__device__ __forceinline__ void zero_acc(f32x4 a0[8], f32x4 a1[8]) {
#pragma unroll
  for (int r = 0; r < 8; ++r)
#pragma unroll
    for (int j = 0; j < 4; ++j) { a0[r][j] = 0.0f; a1[r][j] = 0.0f; }
}

// One K=256 pass, wave tile 128 rows x 32 cols: two 16-col tiles (acc0/acc1)
// share every A-fragment ds_read (2:1 MFMA:ds_read).
//
// CROSS-LAYER PERSISTENT STAGING: g0/g1 (4 slots x 4 float2 per col = 64
// VGPRs) arrive holding THIS pass's kt=0..3 weight batches.  Slot kt&3 is
// consumed (packed) then refilled: kt<4 -> this pass's kt+4; kt>=4 (PF) ->
// the NEXT pass's kt-4.  On exit g holds the next pass's kt=0..3, so the
// weight stream for layer i+1 is in flight DURING layer i's MFMA phase and
// across the barrier -- no cold post-barrier load stall.
template <bool PF>
__device__ __forceinline__ void accum_pass(f32x4 acc0[8], f32x4 acc1[8],
                                           const uint16_t* __restrict__ Ab,
                                           const float* __restrict__ w0,
                                           const float* __restrict__ w1,
                                           const float* __restrict__ nx0,
                                           const float* __restrict__ nx1,
                                           float2 g0[4][4], float2 g1[4][4]) {
#pragma unroll
  for (int kt = 0; kt < 8; ++kt) {
    const int s = kt & 3;
    const short8 b0 = pk8f2(g0[s]);
    const short8 b1 = pk8f2(g1[s]);
    if (kt < 4) {
#pragma unroll
      for (int i = 0; i < 4; ++i) {
        g0[s][i] = reinterpret_cast<const float2*>(w0 + (kt + 4) * 32)[i];
        g1[s][i] = reinterpret_cast<const float2*>(w1 + (kt + 4) * 32)[i];
      }
    } else if (PF) {
#pragma unroll
      for (int i = 0; i < 4; ++i) {
        g0[s][i] = reinterpret_cast<const float2*>(nx0 + (kt - 4) * 32)[i];
        g1[s][i] = reinterpret_cast<const float2*>(nx1 + (kt - 4) * 32)[i];
      }
    }
#pragma unroll
    for (int rt = 0; rt < 8; ++rt) {
      const short8 a =
          *reinterpret_cast<const short8*>(Ab + rt * 16 * APITCH + kt * 32);
      acc0[rt] = __builtin_amdgcn_mfma_f32_16x16x32_bf16(a, b0, acc0[rt], 0, 0, 0);
      acc1[rt] = __builtin_amdgcn_mfma_f32_16x16x32_bf16(a, b1, acc1[rt], 0, 0, 0);
    }
  }
}

// C/D layout (m89): col = lane&15, row = (lane>>4)*4 + j
__device__ __forceinline__ void epi2(const f32x4 acc0[8], const f32x4 acc1[8],
                                     float b0, float b1,
                                     uint16_t* __restrict__ B, int ct0, int ct1,
                                     int lg) {
#pragma unroll
  for (int rt = 0; rt < 8; ++rt) {
#pragma unroll
    for (int j = 0; j < 4; ++j) {
      const int row = rt * 16 + lg * 4 + j;
      float v0 = acc0[rt][j] + b0; v0 = (v0 > 0.0f) ? v0 : 0.01f * v0;
      float v1 = acc1[rt][j] + b1; v1 = (v1 > 0.0f) ? v1 : 0.01f * v1;
      B[row * APITCH + ct0] = f2b_fast(v0);
      B[row * APITCH + ct1] = f2b_fast(v1);
    }
  }
}

__global__ void __launch_bounds__(512, 2)
pn_kernel(const float* __restrict__ obs, const float* __restrict__ action,
          const float* __restrict__ w, const float* __restrict__ omin,
          const float* __restrict__ omax, float* __restrict__ out)
{
  // SINGLE activation buffer: 128 x 264 bf16 = 67584 B -> 2 blocks/CU
  // (LDS-limited), 16 waves/CU, 256-VGPR budget (no spill).
  __shared__ __align__(16) uint16_t B1[RB * APITCH];

  const int tid  = threadIdx.x;
  const int lane = tid & 63;
  const int wid  = tid >> 6;        // 0..7
  const int lr   = lane & 15;
  const int lg   = lane >> 4;
  const int ct0  = wid * 32 + lr;   // first 16-col tile's column
  const int ct1  = ct0 + 16;        // second tile's column

  // XCD swizzle: a member's 4 chunk-blocks land on the same XCD -> member
  // weights fetched into one L2 and served to all 4 readers.
  const int bid    = blockIdx.x;
  const int xcd    = bid & 7;
  const int j5     = bid >> 3;           // 0..63
  const int member = xcd * 16 + (j5 >> 2);
  const int chunk  = j5 & 3;
  const int n0     = chunk * RB;
  const float* wm  = w + (size_t)member * WTOTAL;

  const uint16_t* Ab = B1 + lr * APITCH + lg * 8;

  // per-layer weight row pointers (k-offset lg*8 folded in)
  const float* wt0 = wm + OFF_WTGT + ct0 * 512 + lg * 8;   // tgt pass 1
  const float* wt1 = wm + OFF_WTGT + ct1 * 512 + lg * 8;
  const float* wu0 = wt0 + 256;                            // tgt pass 2
  const float* wu1 = wt1 + 256;
  const float* wa0 = wm + OFF_WS0 + ct0 * 256 + lg * 8;    // hidden 0
  const float* wa1 = wm + OFF_WS0 + ct1 * 256 + lg * 8;
  const float* wb0 = wm + OFF_WS1 + ct0 * 256 + lg * 8;    // hidden 1
  const float* wb1 = wm + OFF_WS1 + ct1 * 256 + lg * 8;
  const float* wc0 = wm + OFF_WS2 + ct0 * 256 + lg * 8;    // hidden 2
  const float* wc1 = wm + OFF_WS2 + ct1 * 256 + lg * 8;

  // ---- kernel-top prologue: start ALL first-round weight streams now ----
  // (1) prime g with tgt-pass-1 kt=0..3  (obs-layer compute covers latency)
  float2 g0[4][4], g1[4][4];
#pragma unroll
  for (int d = 0; d < 4; ++d) {
#pragma unroll
    for (int i = 0; i < 4; ++i) {
      g0[d][i] = reinterpret_cast<const float2*>(wt0 + d * 32)[i];
      g1[d][i] = reinterpret_cast<const float2*>(wt1 + d * 32)[i];
    }
  }
  // (2) act-layer weights stashed in regs until the act phase
  float2 fa0[4], fa1[4];
#pragma unroll
  for (int i = 0; i < 4; ++i) {
    fa0[i] = reinterpret_cast<const float2*>(wm + OFF_WACT + ct0 * 8 + lg * 8)[i];
    fa1[i] = reinterpret_cast<const float2*>(wm + OFF_WACT + ct1 * 8 + lg * 8)[i];
  }

  // ---- obs layer: o = lrelu(W_obs @ x + b_obs) -> B1   (K=32, per-rt)
  {
    // normalization for this lane's k-cols (lg*8 + i): x = obs*s + o
    float sc[8], of[8];
#pragma unroll
    for (int i = 0; i < 8; ++i) {
      const float mn = omin[lg * 8 + i], mx = omax[lg * 8 + i];
      const float s = 2.0f / (mx - mn);
      sc[i] = s;
      of[i] = -mn * s - 1.0f;
    }
    float2 fb0[4], fb1[4];
#pragma unroll
    for (int i = 0; i < 4; ++i) {
      fb0[i] = reinterpret_cast<const float2*>(wm + OFF_WOBS + ct0 * 32 + lg * 8)[i];
      fb1[i] = reinterpret_cast<const float2*>(wm + OFF_WOBS + ct1 * 32 + lg * 8)[i];
    }
    const short8 b0 = pk8f2(fb0);
    const short8 b1 = pk8f2(fb1);
    const float bb0 = wm[OFF_BOBS + ct0], bb1 = wm[OFF_BOBS + ct1];
#pragma unroll
    for (int rt = 0; rt < 8; ++rt) {
      const int n = n0 + rt * 16 + lr;
      const float4 x0 = *reinterpret_cast<const float4*>(obs + n * 32 + lg * 8);
      const float4 x1 = *reinterpret_cast<const float4*>(obs + n * 32 + lg * 8 + 4);
      union { uint32_t u[4]; short8 s; } afr;
      afr.u[0] = pkbf2(x0.x * sc[0] + of[0], x0.y * sc[1] + of[1]);
      afr.u[1] = pkbf2(x0.z * sc[2] + of[2], x0.w * sc[3] + of[3]);
      afr.u[2] = pkbf2(x1.x * sc[4] + of[4], x1.y * sc[5] + of[5]);
      afr.u[3] = pkbf2(x1.z * sc[6] + of[6], x1.w * sc[7] + of[7]);
      f32x4 a0 = {0.0f, 0.0f, 0.0f, 0.0f}, a1 = {0.0f, 0.0f, 0.0f, 0.0f};
      a0 = __builtin_amdgcn_mfma_f32_16x16x32_bf16(afr.s, b0, a0, 0, 0, 0);
      a1 = __builtin_amdgcn_mfma_f32_16x16x32_bf16(afr.s, b1, a1, 0, 0, 0);
#pragma unroll
      for (int j = 0; j < 4; ++j) {
        float v0 = a0[j] + bb0; v0 = (v0 > 0.0f) ? v0 : 0.01f * v0;
        float v1 = a1[j] + bb1; v1 = (v1 > 0.0f) ? v1 : 0.01f * v1;
        B1[(rt * 16 + lg * 4 + j) * APITCH + ct0] = f2b_fast(v0);
        B1[(rt * 16 + lg * 4 + j) * APITCH + ct1] = f2b_fast(v1);
      }
    }
  }
  __syncthreads();                                   // (1) o ready

  f32x4 acc0[8], acc1[8];
  zero_acc(acc0, acc1);

  // ---- tgt pass 1: k = 0..255 over o    (prefetches tgt pass 2)
  accum_pass<true>(acc0, acc1, Ab, wt0, wt1, wu0, wu1, g0, g1);
  __syncthreads();                                   // (2) all reads of o done

  // ---- act layer: a = lrelu(W_act @ action + b_act) -> B1 (overwrite o).
  // K=32 padded: A-frag is zero for lg>0, so junk B values there multiply 0.
  {
    const short8 b0 = pk8f2(fa0);
    const short8 b1 = pk8f2(fa1);
    const float bb0 = wm[OFF_BACT + ct0], bb1 = wm[OFF_BACT + ct1];
#pragma unroll
    for (int rt = 0; rt < 8; ++rt) {
      const int n = n0 + rt * 16 + lr;
      union { uint32_t u[4]; short8 s; } afr;
      if (lg == 0) {
        const float4 q0 = *reinterpret_cast<const float4*>(action + n * 8);
        const float4 q1 = *reinterpret_cast<const float4*>(action + n * 8 + 4);
        afr.u[0] = pkbf2(q0.x, q0.y);
        afr.u[1] = pkbf2(q0.z, q0.w);
        afr.u[2] = pkbf2(q1.x, q1.y);
        afr.u[3] = pkbf2(q1.z, q1.w);
      } else {
        afr.u[0] = afr.u[1] = afr.u[2] = afr.u[3] = 0u;
      }
      f32x4 a0 = {0.0f, 0.0f, 0.0f, 0.0f}, a1 = {0.0f, 0.0f, 0.0f, 0.0f};
      a0 = __builtin_amdgcn_mfma_f32_16x16x32_bf16(afr.s, b0, a0, 0, 0, 0);
      a1 = __builtin_amdgcn_mfma_f32_16x16x32_bf16(afr.s, b1, a1, 0, 0, 0);
#pragma unroll
      for (int j = 0; j < 4; ++j) {
        float v0 = a0[j] + bb0; v0 = (v0 > 0.0f) ? v0 : 0.01f * v0;
        float v1 = a1[j] + bb1; v1 = (v1 > 0.0f) ? v1 : 0.01f * v1;
        B1[(rt * 16 + lg * 4 + j) * APITCH + ct0] = f2b_fast(v0);
        B1[(rt * 16 + lg * 4 + j) * APITCH + ct1] = f2b_fast(v1);
      }
    }
  }
  __syncthreads();                                   // (3) a ready

  // ---- tgt pass 2: k = 256..511 over a   (prefetches hidden 0)
  accum_pass<true>(acc0, acc1, Ab, wu0, wu1, wa0, wa1, g0, g1);
  __syncthreads();                                   // (4) reads of a done
  epi2(acc0, acc1, wm[OFF_BTGT + ct0], wm[OFF_BTGT + ct1], B1, ct0, ct1, lg);
  __syncthreads();                                   // (5) y0 ready

  // ---- hidden 0 (in-place B1)            (prefetches hidden 1)
  zero_acc(acc0, acc1);
  accum_pass<true>(acc0, acc1, Ab, wa0, wa1, wb0, wb1, g0, g1);
  __syncthreads();                                   // (6) reads done
  epi2(acc0, acc1, wm[OFF_BS0 + ct0], wm[OFF_BS0 + ct1], B1, ct0, ct1, lg);
  __syncthreads();                                   // (7) y1 ready

  // ---- hidden 1                          (prefetches hidden 2)
  zero_acc(acc0, acc1);
  accum_pass<true>(acc0, acc1, Ab, wb0, wb1, wc0, wc1, g0, g1);
  __syncthreads();                                   // (8)
  epi2(acc0, acc1, wm[OFF_BS1 + ct0], wm[OFF_BS1 + ct1], B1, ct0, ct1, lg);
  __syncthreads();                                   // (9)

  // ---- hidden 2                          (no further prefetch)
  zero_acc(acc0, acc1);
  accum_pass<false>(acc0, acc1, Ab, wc0, wc1, wc0, wc1, g0, g1);
  __syncthreads();                                   // (10)
  epi2(acc0, acc1, wm[OFF_BS2 + ct0], wm[OFF_BS2 + ct1], B1, ct0, ct1, lg);
  __syncthreads();                                   // (11) final y ready

  // ---- head: wid0 -> state cols 0..31 (two tiles); wid1 tile0 ->
  // reward (lr==0 -> col 32), done (lr==1 -> col 33)
  if (wid < 2) {
    zero_acc(acc0, acc1);
#pragma unroll
    for (int kt = 0; kt < 8; ++kt) {
      short8 b0, b1;
      {
        union { uint32_t u[4]; short8 s; } z;
        z.u[0] = z.u[1] = z.u[2] = z.u[3] = 0u;
        b0 = z.s; b1 = z.s;
      }
      if (wid == 0) {
        float2 f0[4], f1[4];
#pragma unroll
        for (int i = 0; i < 4; ++i) {
          f0[i] = reinterpret_cast<const float2*>(
                      wm + OFF_WSTATE + ct0 * 256 + kt * 32 + lg * 8)[i];
          f1[i] = reinterpret_cast<const float2*>(
                      wm + OFF_WSTATE + ct1 * 256 + kt * 32 + lg * 8)[i];
        }
        b0 = pk8f2(f0);
        b1 = pk8f2(f1);
      } else if (lr == 0) {
        float2 f0[4];
#pragma unroll
        for (int i = 0; i < 4; ++i)
          f0[i] = reinterpret_cast<const float2*>(wm + OFF_WREW + kt * 32 + lg * 8)[i];
        b0 = pk8f2(f0);
      } else if (lr == 1) {
        const float* p = wm + OFF_WDONE + kt * 32 + lg * 8;  // odd offset: scalar
        union { uint32_t u[4]; short8 s; } r;
#pragma unroll
        for (int i = 0; i < 4; ++i) r.u[i] = pkbf2(p[2 * i], p[2 * i + 1]);
        b0 = r.s;
      }
#pragma unroll
      for (int rt = 0; rt < 8; ++rt) {
        const short8 a =
            *reinterpret_cast<const short8*>(Ab + rt * 16 * APITCH + kt * 32);
        acc0[rt] = __builtin_amdgcn_mfma_f32_16x16x32_bf16(a, b0, acc0[rt], 0, 0, 0);
        if (wid == 0)
          acc1[rt] = __builtin_amdgcn_mfma_f32_16x16x32_bf16(a, b1, acc1[rt], 0, 0, 0);
      }
    }

    // ---- head epilogue: f32 residual + un-normalize + tanh/sigmoid
    if (wid == 0) {
      const float mn0 = omin[ct0], rg0 = omax[ct0] - mn0;
      const float mn1 = omin[ct1], rg1 = omax[ct1] - mn1;
      const float bs0 = wm[OFF_BSTATE + ct0], bs1 = wm[OFF_BSTATE + ct1];
#pragma unroll
      for (int rt = 0; rt < 8; ++rt) {
#pragma unroll
        for (int j = 0; j < 4; ++j) {
          const int n = n0 + rt * 16 + lg * 4 + j;
          const float x0 = 2.0f * (obs[n * 32 + ct0] - mn0) / rg0 - 1.0f;
          const float x1 = 2.0f * (obs[n * 32 + ct1] - mn1) / rg1 - 1.0f;
          float v0 = acc0[rt][j] + bs0 + x0;
          float v1 = acc1[rt][j] + bs1 + x1;
          v0 = (v0 + 1.0f) * 0.5f;
          v1 = (v1 + 1.0f) * 0.5f;
          out[((size_t)n * NMEM + member) * 32 + ct0] = v0 * rg0 + mn0;
          out[((size_t)n * NMEM + member) * 32 + ct1] = v1 * rg1 + mn1;
        }
      }
    } else {
      const float br = wm[OFF_BREW], bd = wm[OFF_BDONE];
#pragma unroll
      for (int rt = 0; rt < 8; ++rt) {
#pragma unroll
        for (int j = 0; j < 4; ++j) {
          const int n = n0 + rt * 16 + lg * 4 + j;
          if (lr == 0) {
            out[(size_t)OUT_REW + (size_t)n * NMEM + member] = tanhf(acc0[rt][j] + br);
          } else if (lr == 1) {
            out[(size_t)OUT_DONE + (size_t)n * NMEM + member] =
                1.0f / (1.0f + expf(-(acc0[rt][j] + bd)));
          }
        }
      }
    }
  }
}

extern "C" void kernel_launch(void* const* d_in, const int* in_sizes, int n_in,
                              void* d_out, int out_size, void* d_ws, size_t ws_size,
                              hipStream_t stream) {
  (void)in_sizes; (void)n_in; (void)out_size; (void)d_ws; (void)ws_size;
  const float* obs    = (const float*)d_in[0];
  const float* action = (const float*)d_in[1];
  const float* w      = (const float*)d_in[2];
  const float* omin   = (const float*)d_in[3];
  const float* omax   = (const float*)d_in[4];
  float* out = (float*)d_out;

  pn_kernel<<<dim3(512), dim3(512), 0, stream>>>(obs, action, w, omin, omax, out);
}

// Round 6
// 257.488 us; speedup vs baseline: 1.1456x; 1.1456x over previous
//
#include <hip/hip_runtime.h>
#include <cstdint>
#include <cstddef>

// ---------------- problem constants ----------------
#define NMEM    128          // ensemble size W
#define WTOTAL  348194       // per-member weight row length (floats)

#define OFF_WOBS   0
#define OFF_BOBS   8192
#define OFF_WACT   8448
#define OFF_BACT   10496
#define OFF_WTGT   10752
#define OFF_BTGT   141824
#define OFF_WS0    142080
#define OFF_BS0    207616
#define OFF_WS1    207872
#define OFF_BS1    273408
#define OFF_WS2    273664
#define OFF_BS2    339200
#define OFF_WSTATE 339456
#define OFF_BSTATE 347648
#define OFF_WREW   347680
#define OFF_BREW   347936
#define OFF_WDONE  347937
#define OFF_BDONE  348193

#define OUT_REW  2097152     // 512*128*32
#define OUT_DONE 2162688     // + 512*128

#define RB 128               // rows (batch) per block -> 4 chunks/member
// pitch 264 elems: a wave's b128 A-read spreads evenly over bank quads
// ((lr*33+lg) mod 8 covers all 8 quads, 8 lanes each).
#define APITCH 264
#define WSN 16384            // uint16 elems per weight-stage buffer (256 cols x 64 k)

typedef __attribute__((ext_vector_type(8))) short short8;
typedef __attribute__((ext_vector_type(4))) float f32x4;
typedef __attribute__((ext_vector_type(4))) unsigned int u32x4;

// pack two f32 -> one dword of 2x bf16 (round-half-up): 2 adds + 1 v_perm.
__device__ __forceinline__ uint32_t pkbf2(float lo, float hi) {
  union { float f; uint32_t u; } a, b;
  a.f = lo; b.f = hi;
  return __builtin_amdgcn_perm(b.u + 0x8000u, a.u + 0x8000u, 0x07060302u);
}

__device__ __forceinline__ uint16_t f2b_fast(float f) {
  union { float f; uint32_t u; } x; x.f = f;
  return (uint16_t)((x.u + 0x8000u) >> 16);
}

__device__ __forceinline__ short8 pk8f2(const float2 f[4]) {
  union { uint32_t u[4]; short8 s; } r;
#pragma unroll
  for (int i = 0; i < 4; ++i) r.u[i] = pkbf2(f[i].x, f[i].y);
  return r.s;
}

__device__ __forceinline__ void zero8(f32x4 acc[8]) {
#pragma unroll
  for (int r = 0; r < 8; ++r)
#pragma unroll
    for (int j = 0; j < 4; ++j) acc[r][j] = 0.0f;
}

// pack 16 staged floats -> 2 swizzled b128 LDS writes (one 64-k slice quarter)
__device__ __forceinline__ void ws_commit(const float2 g[8], uint16_t* wsb,
                                          int wsoff0, int wsoff1) {
  uint32_t d[8];
#pragma unroll
  for (int i = 0; i < 8; ++i) d[i] = pkbf2(g[i].x, g[i].y);
  *reinterpret_cast<u32x4*>(wsb + wsoff0) = (u32x4){d[0], d[1], d[2], d[3]};
  *reinterpret_cast<u32x4*>(wsb + wsoff1) = (u32x4){d[4], d[5], d[6], d[7]};
}

// One K=256 pass as 4 double-buffered K=64 slices.
// Per slice: (1) issue next slice's 8 coalesced float2 weight loads (T14
// issue-early), (2) 2x{1 swizzled b128 weight-frag read + 8 A-reads + 8 MFMA}
// from the current buffer, (3) pack+commit next slice (write-late), barrier.
// Load latency tolerance = one full slice of compute.  NX: at s=3 prefetch
// slice 0 of the NEXT pass (np) into WS[0], covered by the inter-layer phase.
// Precondition: this pass's slice 0 already in WS[0], barrier passed.
template <bool NX>
__device__ __forceinline__ void accum_lds(f32x4 acc[8],
                                          const uint16_t* __restrict__ Ab,
                                          uint16_t* __restrict__ WS,
                                          const float* __restrict__ sp,
                                          const float* __restrict__ np,
                                          int wsoff0, int wsoff1,
                                          int wrd, int lrm, int lg) {
#pragma unroll
  for (int s = 0; s < 4; ++s) {
    float2 g[8];
    if (s < 3 || NX) {
      const float* src = (s < 3) ? (sp + (s + 1) * 64) : np;
#pragma unroll
      for (int i = 0; i < 8; ++i)
        g[i] = reinterpret_cast<const float2*>(src)[i];
    }
    const uint16_t* wsr = WS + (s & 1) * WSN + wrd;
#pragma unroll
    for (int h = 0; h < 2; ++h) {
      const short8 b = *reinterpret_cast<const short8*>(
          wsr + (((h * 4 + lg) ^ lrm) * 8));
#pragma unroll
      for (int rt = 0; rt < 8; ++rt) {
        const short8 a = *reinterpret_cast<const short8*>(
            Ab + rt * 16 * APITCH + (s * 2 + h) * 32);
        acc[rt] =
            __builtin_amdgcn_mfma_f32_16x16x32_bf16(a, b, acc[rt], 0, 0, 0);
      }
    }
    if (s < 3 || NX)
      ws_commit(g, WS + ((s + 1) & 1) * WSN, wsoff0, wsoff1);
    __syncthreads();
  }
}

// C/D layout (m89): col = lane&15, row = (lane>>4)*4 + j
__device__ __forceinline__ void epi_lrelu(const f32x4 acc[8], float bv,
                                          uint16_t* __restrict__ B, int c,
                                          int lg) {
#pragma unroll
  for (int rt = 0; rt < 8; ++rt) {
#pragma unroll
    for (int j = 0; j < 4; ++j) {
      float v = acc[rt][j] + bv;
      v = (v > 0.0f) ? v : 0.01f * v;
      B[(rt * 16 + lg * 4 + j) * APITCH + c] = f2b_fast(v);
    }
  }
}

__global__ void __launch_bounds__(1024, 4)
pn_kernel(const float* __restrict__ obs, const float* __restrict__ action,
          const float* __restrict__ w, const float* __restrict__ omin,
          const float* __restrict__ omax, float* __restrict__ out)
{
  // activations 67.6 KB + weight double-buffer 64 KB = 132 KB -> 1 block/CU,
  // 16 waves/CU.
  __shared__ __align__(16) uint16_t B1[RB * APITCH];
  __shared__ __align__(16) uint16_t WS[2 * WSN];

  const int tid  = threadIdx.x;
  const int lane = tid & 63;
  const int wid  = tid >> 6;        // 0..15
  const int lr   = lane & 15;
  const int lg   = lane >> 4;
  const int c    = wid * 16 + lr;   // this lane's output column (0..255)

  // XCD swizzle: a member's 4 chunk-blocks land on the same XCD.
  const int bid    = blockIdx.x;
  const int xcd    = bid & 7;
  const int j5     = bid >> 3;           // 0..63
  const int member = xcd * 16 + (j5 >> 2);
  const int chunk  = j5 & 3;
  const int n0     = chunk * RB;
  const float* wm  = w + (size_t)member * WTOTAL;

  const uint16_t* Ab = B1 + lr * APITCH + lg * 8;

  // ---- weight-stage constants: thread (scol, spart) stages slice floats
  // [scol*stride + s*64 + spart*16, +16) -> bf16 chunks 2p, 2p+1 of col scol,
  // XOR-swizzled by col&7 for bank spread.
  const int scol   = tid >> 2;          // 0..255
  const int spart  = tid & 3;           // 0..3
  const int wsoff0 = scol * 64 + (((2 * spart)     ^ (scol & 7)) * 8);
  const int wsoff1 = scol * 64 + (((2 * spart + 1) ^ (scol & 7)) * 8);
  const float* sp_t1 = wm + OFF_WTGT + scol * 512 + spart * 16;  // tgt k 0..255
  const float* sp_t2 = sp_t1 + 256;                              // tgt k 256..511
  const float* sp_h0 = wm + OFF_WS0 + scol * 256 + spart * 16;
  const float* sp_h1 = wm + OFF_WS1 + scol * 256 + spart * 16;
  const float* sp_h2 = wm + OFF_WS2 + scol * 256 + spart * 16;
  // consumer-side read constants
  const int wrd = c * 64;
  const int lrm = lr & 7;               // == c & 7

  // ---- prologue: issue tgt-pass-1 slice 0 loads (committed after obs layer)
  float2 gp[8];
#pragma unroll
  for (int i = 0; i < 8; ++i)
    gp[i] = reinterpret_cast<const float2*>(sp_t1)[i];

  // ---- obs layer: o = lrelu(W_obs @ x + b_obs) -> B1   (K=32, per-rt)
  {
    float sc[8], of[8];
#pragma unroll
    for (int i = 0; i < 8; ++i) {
      const float mn = omin[lg * 8 + i], mx = omax[lg * 8 + i];
      const float s = 2.0f / (mx - mn);
      sc[i] = s;
      of[i] = -mn * s - 1.0f;
    }
    float2 fb[4];
#pragma unroll
    for (int i = 0; i < 4; ++i)
      fb[i] = reinterpret_cast<const float2*>(wm + OFF_WOBS + c * 32 + lg * 8)[i];
    const short8 b = pk8f2(fb);
    const float bb = wm[OFF_BOBS + c];
#pragma unroll
    for (int rt = 0; rt < 8; ++rt) {
      const int n = n0 + rt * 16 + lr;
      const float4 x0 = *reinterpret_cast<const float4*>(obs + n * 32 + lg * 8);
      const float4 x1 = *reinterpret_cast<const float4*>(obs + n * 32 + lg * 8 + 4);
      union { uint32_t u[4]; short8 s; } afr;
      afr.u[0] = pkbf2(x0.x * sc[0] + of[0], x0.y * sc[1] + of[1]);
      afr.u[1] = pkbf2(x0.z * sc[2] + of[2], x0.w * sc[3] + of[3]);
      afr.u[2] = pkbf2(x1.x * sc[4] + of[4], x1.y * sc[5] + of[5]);
      afr.u[3] = pkbf2(x1.z * sc[6] + of[6], x1.w * sc[7] + of[7]);
      f32x4 a0 = {0.0f, 0.0f, 0.0f, 0.0f};
      a0 = __builtin_amdgcn_mfma_f32_16x16x32_bf16(afr.s, b, a0, 0, 0, 0);
#pragma unroll
      for (int j = 0; j < 4; ++j) {
        float v = a0[j] + bb;
        v = (v > 0.0f) ? v : 0.01f * v;
        B1[(rt * 16 + lg * 4 + j) * APITCH + c] = f2b_fast(v);
      }
    }
  }
  // commit tgt-pass-1 slice 0 into WS[0]
  ws_commit(gp, WS, wsoff0, wsoff1);
  __syncthreads();                      // (1) o ready + WS[0] slice0 ready

  f32x4 acc[8];
  zero8(acc);

  // ---- tgt pass 1: k = 0..255 over o   (s=3 prefetches tgt pass 2 slice 0)
  accum_lds<true>(acc, Ab, WS, sp_t1, sp_t2, wsoff0, wsoff1, wrd, lrm, lg);

  // ---- act layer: a = lrelu(W_act @ action + b_act) -> B1 (overwrite o).
  // K=32 padded: A-frag is zero for lg>0, so junk B values there multiply 0.
  {
    float2 fb[4];
#pragma unroll
    for (int i = 0; i < 4; ++i)
      fb[i] = reinterpret_cast<const float2*>(wm + OFF_WACT + c * 8 + lg * 8)[i];
    const short8 b = pk8f2(fb);
    const float bb = wm[OFF_BACT + c];
#pragma unroll
    for (int rt = 0; rt < 8; ++rt) {
      const int n = n0 + rt * 16 + lr;
      union { uint32_t u[4]; short8 s; } afr;
      if (lg == 0) {
        const float4 q0 = *reinterpret_cast<const float4*>(action + n * 8);
        const float4 q1 = *reinterpret_cast<const float4*>(action + n * 8 + 4);
        afr.u[0] = pkbf2(q0.x, q0.y);
        afr.u[1] = pkbf2(q0.z, q0.w);
        afr.u[2] = pkbf2(q1.x, q1.y);
        afr.u[3] = pkbf2(q1.z, q1.w);
      } else {
        afr.u[0] = afr.u[1] = afr.u[2] = afr.u[3] = 0u;
      }
      f32x4 a0 = {0.0f, 0.0f, 0.0f, 0.0f};
      a0 = __builtin_amdgcn_mfma_f32_16x16x32_bf16(afr.s, b, a0, 0, 0, 0);
#pragma unroll
      for (int j = 0; j < 4; ++j) {
        float v = a0[j] + bb;
        v = (v > 0.0f) ? v : 0.01f * v;
        B1[(rt * 16 + lg * 4 + j) * APITCH + c] = f2b_fast(v);
      }
    }
  }
  __syncthreads();                      // (2) a ready; WS[0] (tgt2 s0) intact

  // ---- tgt pass 2: k = 256..511 over a  (prefetches hidden-0 slice 0)
  accum_lds<true>(acc, Ab, WS, sp_t2, sp_h0, wsoff0, wsoff1, wrd, lrm, lg);
  epi_lrelu(acc, wm[OFF_BTGT + c], B1, c, lg);
  __syncthreads();                      // (3) y0 ready

  // ---- hidden 0 (in-place B1)           (prefetches hidden 1)
  zero8(acc);
  accum_lds<true>(acc, Ab, WS, sp_h0, sp_h1, wsoff0, wsoff1, wrd, lrm, lg);
  epi_lrelu(acc, wm[OFF_BS0 + c], B1, c, lg);
  __syncthreads();                      // (4) y1 ready

  // ---- hidden 1                         (prefetches hidden 2)
  zero8(acc);
  accum_lds<true>(acc, Ab, WS, sp_h1, sp_h2, wsoff0, wsoff1, wrd, lrm, lg);
  epi_lrelu(acc, wm[OFF_BS1 + c], B1, c, lg);
  __syncthreads();                      // (5) y2 ready

  // ---- hidden 2                         (no further prefetch)
  zero8(acc);
  accum_lds<false>(acc, Ab, WS, sp_h2, sp_h2, wsoff0, wsoff1, wrd, lrm, lg);
  epi_lrelu(acc, wm[OFF_BS2 + c], B1, c, lg);
  __syncthreads();                      // (6) final y ready

  // ---- head: cols 0..31 = w_state, 32 = w_reward, 33 = w_done  (K=256)
  if (wid < 3) {
    zero8(acc);
#pragma unroll
    for (int kt = 0; kt < 8; ++kt) {
      short8 b;
      if (c < 32) {
        const float* p = wm + OFF_WSTATE + c * 256 + kt * 32 + lg * 8;
        float2 f[4];
#pragma unroll
        for (int i = 0; i < 4; ++i) f[i] = reinterpret_cast<const float2*>(p)[i];
        b = pk8f2(f);
      } else if (c == 32) {
        const float* p = wm + OFF_WREW + kt * 32 + lg * 8;
        float2 f[4];
#pragma unroll
        for (int i = 0; i < 4; ++i) f[i] = reinterpret_cast<const float2*>(p)[i];
        b = pk8f2(f);
      } else if (c == 33) {
        const float* p = wm + OFF_WDONE + kt * 32 + lg * 8;  // odd offset
        union { uint32_t u[4]; short8 s; } r;
#pragma unroll
        for (int i = 0; i < 4; ++i) r.u[i] = pkbf2(p[2 * i], p[2 * i + 1]);
        b = r.s;
      } else {
        union { uint32_t u[4]; short8 s; } z;
        z.u[0] = z.u[1] = z.u[2] = z.u[3] = 0u;
        b = z.s;
      }
#pragma unroll
      for (int rt = 0; rt < 8; ++rt) {
        const short8 a =
            *reinterpret_cast<const short8*>(Ab + rt * 16 * APITCH + kt * 32);
        acc[rt] = __builtin_amdgcn_mfma_f32_16x16x32_bf16(a, b, acc[rt], 0, 0, 0);
      }
    }

    // ---- head epilogue: f32 residual + un-normalize + tanh/sigmoid
    if (c < 34) {
#pragma unroll
      for (int rt = 0; rt < 8; ++rt) {
#pragma unroll
        for (int j = 0; j < 4; ++j) {
          const int n = n0 + rt * 16 + lg * 4 + j;
          float v = acc[rt][j];
          if (c < 32) {
            const float mn = omin[c], mx = omax[c];
            const float rng = mx - mn;
            const float x = 2.0f * (obs[n * 32 + c] - mn) / rng - 1.0f;
            v += wm[OFF_BSTATE + c] + x;
            v = (v + 1.0f) * 0.5f;
            out[((size_t)n * NMEM + member) * 32 + c] = v * rng + mn;
          } else if (c == 32) {
            v += wm[OFF_BREW];
            out[(size_t)OUT_REW + (size_t)n * NMEM + member] = tanhf(v);
          } else {  // c == 33
            v += wm[OFF_BDONE];
            out[(size_t)OUT_DONE + (size_t)n * NMEM + member] =
                1.0f / (1.0f + expf(-v));
          }
        }
      }
    }
  }
}

extern "C" void kernel_launch(void* const* d_in, const int* in_sizes, int n_in,
                              void* d_out, int out_size, void* d_ws, size_t ws_size,
                              hipStream_t stream) {
  (void)in_sizes; (void)n_in; (void)out_size; (void)d_ws; (void)ws_size;
  const float* obs    = (const float*)d_in[0];
  const float* action = (const float*)d_in[1];
  const float* w      = (const float*)d_in[2];
  const float* omin   = (const float*)d_in[3];
  const float* omax   = (const float*)d_in[4];
  float* out = (float*)d_out;

  pn_kernel<<<dim3(512), dim3(1024), 0, stream>>>(obs, action, w, omin, omax, out);
}

// Round 7
// 129.539 us; speedup vs baseline: 2.2771x; 1.9877x over previous
//
#include <hip/hip_runtime.h>
#include <cstdint>
#include <cstddef>

// ---------------- problem constants ----------------
#define SCALE_F 1.0f
#define NMEM    128          // ensemble size W
#define WTOTAL  348194       // per-member weight row length (floats)

#define OFF_WOBS   0
#define OFF_BOBS   8192
#define OFF_WACT   8448
#define OFF_BACT   10496
#define OFF_WTGT   10752
#define OFF_BTGT   141824
#define OFF_WS0    142080
#define OFF_BS0    207616
#define OFF_WS1    207872
#define OFF_BS1    273408
#define OFF_WS2    273664
#define OFF_BS2    339200
#define OFF_WSTATE 339456
#define OFF_BSTATE 347648
#define OFF_WREW   347680
#define OFF_BREW   347936
#define OFF_WDONE  347937
#define OFF_BDONE  348193

#define OUT_REW  2097152     // 512*128*32
#define OUT_DONE 2162688     // + 512*128

#define RB 128               // rows (batch) per block

// activation pitch 264 elems = 132 dwords == 4 mod 32 -> row-column reads are
// ~2-way bank aliasing (free per m136).
#define APITCH 264
#define XPITCH 72

typedef __attribute__((ext_vector_type(8))) short short8;
typedef __attribute__((ext_vector_type(4))) float f32x4;

// pack two f32 -> one dword of 2x bf16 (round-half-up): 2 adds + 1 v_perm.
// (Replaces the 4-op RNE f2b of the 130.6us baseline; rounds 1-6 all passed
// with this rounding at identical absmax 0.03125.)
__device__ __forceinline__ uint32_t pkbf2(float lo, float hi) {
  union { float f; uint32_t u; } a, b;
  a.f = lo; b.f = hi;
  return __builtin_amdgcn_perm(b.u + 0x8000u, a.u + 0x8000u, 0x07060302u);
}

__device__ __forceinline__ uint16_t f2b_fast(float f) {
  union { float f; uint32_t u; } x; x.f = f;
  return (uint16_t)((x.u + 0x8000u) >> 16);
}

__device__ __forceinline__ short8 pk8f2(const float2 f[4]) {
  union { uint32_t u[4]; short8 s; } r;
#pragma unroll
  for (int i = 0; i < 4; ++i) r.u[i] = pkbf2(f[i].x, f[i].y);
  return r.s;
}

__device__ __forceinline__ void zero8(f32x4 acc[8]) {
#pragma unroll
  for (int r = 0; r < 8; ++r)
#pragma unroll
    for (int j = 0; j < 4; ++j) acc[r][j] = 0.0f;
}

// One K=256 pass: wave tile 128 rows x 16 cols.
// ALL 32 weight float2-loads are issued up front into a statically-indexed
// register array so 32 independent VMEM chains are in flight; cvt+MFMA then
// consume them in order.  Weight base is 8B-aligned (WTOTAL % 4 == 2).
__device__ __forceinline__ void accum_k8(f32x4 acc[8], const uint16_t* Abase,
                                         const float* wrow) {
  float2 f[8][4];
#pragma unroll
  for (int kt = 0; kt < 8; ++kt)
#pragma unroll
    for (int i = 0; i < 4; ++i)
      f[kt][i] = reinterpret_cast<const float2*>(wrow + kt * 32)[i];

#pragma unroll
  for (int kt = 0; kt < 8; ++kt) {
    const short8 b = pk8f2(f[kt]);
#pragma unroll
    for (int rt = 0; rt < 8; ++rt) {
      const short8 a =
          *reinterpret_cast<const short8*>(Abase + rt * 16 * APITCH + kt * 32);
      acc[rt] = __builtin_amdgcn_mfma_f32_16x16x32_bf16(a, b, acc[rt], 0, 0, 0);
    }
  }
}

// C/D layout (m89): col = lane&15, row = (lane>>4)*4 + j
__device__ __forceinline__ void epi_lrelu(const f32x4 acc[8], float bv,
                                          uint16_t* Bout, int c, int lg) {
#pragma unroll
  for (int rt = 0; rt < 8; ++rt) {
#pragma unroll
    for (int j = 0; j < 4; ++j) {
      float v = acc[rt][j] + bv;
      v = (v > 0.0f) ? v : 0.01f * v;  // leaky_relu
      Bout[(rt * 16 + lg * 4 + j) * APITCH + c] = f2b_fast(v);
    }
  }
}

__global__ void __launch_bounds__(1024, 4)
pn_kernel(const float* __restrict__ obs, const float* __restrict__ action,
          const float* __restrict__ w, const float* __restrict__ omin,
          const float* __restrict__ omax, float* __restrict__ out)
{
  __shared__ __align__(16) uint16_t xa[RB * XPITCH];  // 18 KB
  __shared__ __align__(16) uint16_t B1[RB * APITCH];  // 66 KB
  __shared__ __align__(16) uint16_t B2[RB * APITCH];  // 66 KB  -> 150 KB total

  const int tid  = threadIdx.x;
  const int lane = tid & 63;
  const int wid  = tid >> 6;
  const int lr   = lane & 15;
  const int lg   = lane >> 4;
  const int c    = wid * 16 + lr;   // this lane's output column (0..255)

  // XCD swizzle: a member's 4 chunk-blocks land on the same XCD in the same
  // dispatch round, layer-synchronized -> per-layer L2 working set
  // 8 members x 256KB = 2MB < 4MB -> weights hit HBM once per XCD.
  const int bid    = blockIdx.x;
  const int xcd    = bid & 7;
  const int j5     = bid >> 3;           // 0..63
  const int member = xcd * 16 + (j5 >> 2);
  const int chunk  = j5 & 3;
  const int n0     = chunk * RB;
  const float* wm  = w + (size_t)member * WTOTAL;

  // ---- phase 0: xa[128][64] = [x(32) | action(8) | zeros(24)] bf16
  {
    const int row = tid >> 3, seg = tid & 7;   // 128 rows x 8 segs = 1024
    const int n = n0 + row;
    float v[8];
    if (seg < 4) {
      const int c0 = seg * 8;
#pragma unroll
      for (int i = 0; i < 8; ++i) {
        const float mn = omin[c0 + i], mx = omax[c0 + i];
        v[i] = (2.0f * (obs[n * 32 + c0 + i] - mn) / (mx - mn) - 1.0f) * SCALE_F;
      }
    } else if (seg == 4) {
#pragma unroll
      for (int i = 0; i < 8; ++i) v[i] = action[n * 8 + i];
    } else {
#pragma unroll
      for (int i = 0; i < 8; ++i) v[i] = 0.0f;
    }
    union { uint32_t u[4]; short8 s; } sv;
#pragma unroll
    for (int i = 0; i < 4; ++i) sv.u[i] = pkbf2(v[2 * i], v[2 * i + 1]);
    *reinterpret_cast<short8*>(xa + row * XPITCH + seg * 8) = sv.s;
  }
  __syncthreads();

  // ---- obs layer: o = W_obs @ x + b_obs, lrelu -> B1   (K=32)
  {
    f32x4 acc[8];
    zero8(acc);
    float2 f[4];
#pragma unroll
    for (int i = 0; i < 4; ++i)
      f[i] = reinterpret_cast<const float2*>(wm + OFF_WOBS + c * 32 + lg * 8)[i];
    const short8 b = pk8f2(f);
#pragma unroll
    for (int rt = 0; rt < 8; ++rt) {
      const short8 a =
          *reinterpret_cast<const short8*>(xa + (rt * 16 + lr) * XPITCH + lg * 8);
      acc[rt] = __builtin_amdgcn_mfma_f32_16x16x32_bf16(a, b, acc[rt], 0, 0, 0);
    }
    epi_lrelu(acc, wm[OFF_BOBS + c], B1, c, lg);
  }

  // ---- act layer: a = W_act @ action + b_act, lrelu -> B2  (K=32 padded;
  // xa cols 40..63 are zero so lg>=1 weight values are multiplied by 0)
  {
    f32x4 acc[8];
    zero8(acc);
    float2 f[4];
#pragma unroll
    for (int i = 0; i < 4; ++i)
      f[i] = reinterpret_cast<const float2*>(wm + OFF_WACT + c * 8 + lg * 8)[i];
    const short8 b = pk8f2(f);
#pragma unroll
    for (int rt = 0; rt < 8; ++rt) {
      const short8 a = *reinterpret_cast<const short8*>(
          xa + (rt * 16 + lr) * XPITCH + 32 + lg * 8);
      acc[rt] = __builtin_amdgcn_mfma_f32_16x16x32_bf16(a, b, acc[rt], 0, 0, 0);
    }
    epi_lrelu(acc, wm[OFF_BACT + c], B2, c, lg);
  }
  __syncthreads();   // B1 (o), B2 (a) visible; xa dead

  // ---- tgt layer: K=512 = concat[o|a]; pass1 from B1, pass2 from B2 -> B1
  {
    f32x4 acc[8];
    zero8(acc);
    accum_k8(acc, B1 + lr * APITCH + lg * 8, wm + OFF_WTGT + c * 512 + lg * 8);
    __syncthreads();  // all waves done reading B1 -> safe to overwrite
    accum_k8(acc, B2 + lr * APITCH + lg * 8,
             wm + OFF_WTGT + c * 512 + 256 + lg * 8);
    epi_lrelu(acc, wm[OFF_BTGT + c], B1, c, lg);
  }
  __syncthreads();

  // ---- hidden 0: B1 -> B2
  {
    f32x4 acc[8];
    zero8(acc);
    accum_k8(acc, B1 + lr * APITCH + lg * 8, wm + OFF_WS0 + c * 256 + lg * 8);
    epi_lrelu(acc, wm[OFF_BS0 + c], B2, c, lg);
  }
  __syncthreads();

  // ---- hidden 1: B2 -> B1
  {
    f32x4 acc[8];
    zero8(acc);
    accum_k8(acc, B2 + lr * APITCH + lg * 8, wm + OFF_WS1 + c * 256 + lg * 8);
    epi_lrelu(acc, wm[OFF_BS1 + c], B1, c, lg);
  }
  __syncthreads();

  // ---- hidden 2: B1 -> B2
  {
    f32x4 acc[8];
    zero8(acc);
    accum_k8(acc, B1 + lr * APITCH + lg * 8, wm + OFF_WS2 + c * 256 + lg * 8);
    epi_lrelu(acc, wm[OFF_BS2 + c], B2, c, lg);
  }
  __syncthreads();

  // ---- head: cols 0..31 = w_state, 32 = w_reward, 33 = w_done  (K=256)
  if (wid < 3) {
    f32x4 acc[8];
    zero8(acc);
#pragma unroll
    for (int kt = 0; kt < 8; ++kt) {
      short8 b;
      if (c < 32) {
        const float* p = wm + OFF_WSTATE + c * 256 + kt * 32 + lg * 8;
        float2 f[4];
#pragma unroll
        for (int i = 0; i < 4; ++i) f[i] = reinterpret_cast<const float2*>(p)[i];
        b = pk8f2(f);
      } else if (c == 32) {
        const float* p = wm + OFF_WREW + kt * 32 + lg * 8;
        float2 f[4];
#pragma unroll
        for (int i = 0; i < 4; ++i) f[i] = reinterpret_cast<const float2*>(p)[i];
        b = pk8f2(f);
      } else if (c == 33) {
        const float* p = wm + OFF_WDONE + kt * 32 + lg * 8;  // odd offset: scalar
        union { uint32_t u[4]; short8 s; } r;
#pragma unroll
        for (int i = 0; i < 4; ++i) r.u[i] = pkbf2(p[2 * i], p[2 * i + 1]);
        b = r.s;
      } else {
        union { uint32_t u[4]; short8 s; } z;
        z.u[0] = z.u[1] = z.u[2] = z.u[3] = 0u;
        b = z.s;
      }
#pragma unroll
      for (int rt = 0; rt < 8; ++rt) {
        const short8 a = *reinterpret_cast<const short8*>(
            B2 + (rt * 16 + lr) * APITCH + kt * 32 + lg * 8);
        acc[rt] = __builtin_amdgcn_mfma_f32_16x16x32_bf16(a, b, acc[rt], 0, 0, 0);
      }
    }

    // ---- head epilogue: f32 residual + un-normalize + tanh/sigmoid
    if (c < 34) {
#pragma unroll
      for (int rt = 0; rt < 8; ++rt) {
#pragma unroll
        for (int j = 0; j < 4; ++j) {
          const int n = n0 + rt * 16 + lg * 4 + j;
          float v = acc[rt][j];
          if (c < 32) {
            const float mn = omin[c], mx = omax[c];
            const float rng = mx - mn;
            const float x =
                (2.0f * (obs[n * 32 + c] - mn) / rng - 1.0f) * SCALE_F;
            v += wm[OFF_BSTATE + c] + x;
            v = (v / SCALE_F + 1.0f) * 0.5f;
            out[((size_t)n * NMEM + member) * 32 + c] = v * rng + mn;
          } else if (c == 32) {
            v += wm[OFF_BREW];
            out[(size_t)OUT_REW + n * NMEM + member] = tanhf(v);
          } else {  // c == 33
            v += wm[OFF_BDONE];
            out[(size_t)OUT_DONE + n * NMEM + member] = 1.0f / (1.0f + expf(-v));
          }
        }
      }
    }
  }
}

extern "C" void kernel_launch(void* const* d_in, const int* in_sizes, int n_in,
                              void* d_out, int out_size, void* d_ws, size_t ws_size,
                              hipStream_t stream) {
  (void)in_sizes; (void)n_in; (void)out_size; (void)d_ws; (void)ws_size;
  const float* obs    = (const float*)d_in[0];
  const float* action = (const float*)d_in[1];
  const float* w      = (const float*)d_in[2];
  const float* omin   = (const float*)d_in[3];
  const float* omax   = (const float*)d_in[4];
  float* out = (float*)d_out;

  pn_kernel<<<dim3(512), dim3(1024), 0, stream>>>(obs, action, w, omin, omax, out);
}